// Round 2
// baseline (1452.413 us; speedup 1.0000x reference)
//
#include <hip/hip_runtime.h>
#include <math.h>
#include <stdint.h>

// Problem constants
#define B_ 16
#define N_ 4096
#define C_ 384
#define H_ 8
#define NH_ 512
#define NTOT_ 6144  // B_ * C_ : merged-batch N dimension for GEMM1

typedef __attribute__((ext_vector_type(8))) short short8;
typedef __attribute__((ext_vector_type(4))) float f32x4;

__device__ __forceinline__ unsigned short f2bf(float x) {
  uint32_t u = __builtin_bit_cast(uint32_t, x);
  uint32_t r = (u + 0x7fffu + ((u >> 16) & 1u)) >> 16;
  return (unsigned short)r;
}
__device__ __forceinline__ float bf2f(unsigned short u) {
  uint32_t v = ((uint32_t)u) << 16;
  return __builtin_bit_cast(float, v);
}

__device__ __forceinline__ void gl2lds16(const void* g, void* l) {
  __builtin_amdgcn_global_load_lds((__attribute__((address_space(1))) void*)g,
                                   (__attribute__((address_space(3))) void*)l,
                                   16, 0, 0);
}

__device__ __forceinline__ void phase_mid() {
  __builtin_amdgcn_s_barrier();
  asm volatile("s_waitcnt lgkmcnt(0)" ::: "memory");
  __builtin_amdgcn_s_setprio(1);
}
__device__ __forceinline__ void phase_end() {
  __builtin_amdgcn_s_setprio(0);
  __builtin_amdgcn_s_barrier();
}

// ---------------- fp32 -> bf16 cast (vectorized, 8 elems/thread) -------------
__global__ void cvt_f32_bf16(const float* __restrict__ src,
                             unsigned short* __restrict__ dst, size_t n) {
  size_t i = ((size_t)blockIdx.x * blockDim.x + threadIdx.x) * 8;
  if (i >= n) return;
  float4 a = *(const float4*)(src + i);
  float4 b = *(const float4*)(src + i + 4);
  typedef __attribute__((ext_vector_type(8))) unsigned short u16x8;
  u16x8 o;
  o[0] = f2bf(a.x); o[1] = f2bf(a.y); o[2] = f2bf(a.z); o[3] = f2bf(a.w);
  o[4] = f2bf(b.x); o[5] = f2bf(b.y); o[6] = f2bf(b.z); o[7] = f2bf(b.w);
  *(u16x8*)(dst + i) = o;
}

// ---------------- x [B,4096,384] f32 -> xT [B,384,4096] bf16 -----------------
__global__ __launch_bounds__(256)
void transpose_x(const float* __restrict__ x, unsigned short* __restrict__ xT) {
  __shared__ float tile[64 * 65];
  int b = blockIdx.z;
  int n0 = blockIdx.x * 64;
  int c0 = blockIdx.y * 64;
  int t = threadIdx.x;
  const float* xb = x + (size_t)b * N_ * C_;
  #pragma unroll
  for (int i = 0; i < 16; i++) {
    int r = i * 4 + (t >> 6);
    int cc = t & 63;
    tile[r * 65 + cc] = xb[(size_t)(n0 + r) * C_ + c0 + cc];
  }
  __syncthreads();
  unsigned short* xTb = xT + (size_t)b * C_ * N_;
  #pragma unroll
  for (int i = 0; i < 16; i++) {
    int r = i * 4 + (t >> 6);
    int nn = t & 63;
    xTb[(size_t)(c0 + r) * N_ + n0 + nn] = f2bf(tile[nn * 65 + r]);
  }
}

// ---------------- GEMM1: 256x256 8-phase merged-batch ------------------------
// Out[m][j] = sum_k A[m][k] * Bt[j][k]
// A  [12288, 4096] bf16 (Wqkv), Bt [6144, 4096] bf16 (xT, rows j = b*384+c)
// Out [12288, 6144] bf16 (Y).
// 512 threads = 8 waves (2M x 4N), per-wave 128x64, BK=64, 2 K-tiles/iter.
// LDS 128 KiB: As/Bs [dbuf][half(128 rows)][128*64], XOR-swizzle slot = q^(r&7)
// (staging stays lane-linear; source k-chunk pre-swizzled).
//
// Stagger (re-derived, legality-first; region last-read: Bs0@P2 As0@P3
// Bs1@P6 As1@P7):
//   P1:A1(T+1)  P3:B0(T+2)  P4:{B1,A0}(T+2)+GATE  P5:A1(T+2)
//   P7:B0(T+3)  P8:{B1,A0}(T+3)+GATE
// Gates vmcnt(6): 3 newest half-tiles (6 loads/lane) may stay in flight;
// every half needed in the next 4 phases was issued >=3 phases before the
// gate (min distance 3 vs 2 in the previous, regressed version).
__global__ __launch_bounds__(512, 2)
void gemm256_bt(const unsigned short* __restrict__ A,
                const unsigned short* __restrict__ Bt,
                unsigned short* __restrict__ Out) {
  __shared__ unsigned short As[2][2][128 * 64];
  __shared__ unsigned short Bs[2][2][128 * 64];

  // bijective XCD swizzle (1152 blocks, 1152 % 8 == 0): XCD k gets swz
  // [144k,144k+144): nt sweeps 0..23 at fixed mt -> A-panel (2MB) L2-resident.
  const int bid = blockIdx.x;
  const int swz = (bid & 7) * 144 + (bid >> 3);
  const int mt = swz / 24, nt = swz % 24;   // 48 x 24 tiles
  const int m0 = mt * 256, n0 = nt * 256;

  const int t = threadIdx.x;
  const int lane = t & 63;
  const int w = t >> 6;
  const int quad = lane >> 4;
  const int r16 = lane & 15;
  const int hA = w >> 2;           // which A half this wave reads (0/1)
  const int hB = (w >> 1) & 1;     // which B half this wave reads
  const int rBb = (w & 1) * 64;    // row base within B half
  const int slot0 = quad ^ (r16 & 7);  // k-chunk slot for kk=0
  const int slot1 = slot0 ^ 4;         // kk=1 (quad+4)

  f32x4 acc[8][4];
  #pragma unroll
  for (int i = 0; i < 8; i++)
    #pragma unroll
    for (int j = 0; j < 4; j++)
      acc[i][j] = (f32x4){0.f, 0.f, 0.f, 0.f};

  short8 af[4][2], bl[2][2], bh[2][2];

  // staging: thread t covers rows rs and rs+64 of a 128-row half-tile;
  // LDS dest lane-linear (t*8), source k-chunk pre-swizzled q8 = (t&7)^(rs&7).
  const int rs = t >> 3;
  const int q8 = (t & 7) ^ (rs & 7);
  const unsigned short* aS = A  + (size_t)(m0 + rs) * 4096 + q8 * 8;
  const unsigned short* bS = Bt + (size_t)(n0 + rs) * 4096 + q8 * 8;

  auto stA = [&](int d, int hf, int kt) {
    const unsigned short* s =
        aS + (size_t)hf * (128 * 4096) + (size_t)((kt & 63) * 64);
    unsigned short* dp = &As[d][hf][t * 8];
    gl2lds16(s, dp);
    gl2lds16(s + (size_t)64 * 4096, dp + 4096);
  };
  auto stB = [&](int d, int hf, int kt) {
    const unsigned short* s =
        bS + (size_t)hf * (128 * 4096) + (size_t)((kt & 63) * 64);
    unsigned short* dp = &Bs[d][hf][t * 8];
    gl2lds16(s, dp);
    gl2lds16(s + (size_t)64 * 4096, dp + 4096);
  };
  auto ldAh = [&](int d, int ih) {
    #pragma unroll
    for (int i = 0; i < 4; i++) {
      const unsigned short* base = &As[d][hA][(ih * 64 + i * 16 + r16) * 64];
      af[i][0] = *(const short8*)(base + slot0 * 8);
      af[i][1] = *(const short8*)(base + slot1 * 8);
    }
  };
  auto ldBh = [&](int d, int jh, short8 (&bfr)[2][2]) {
    #pragma unroll
    for (int j = 0; j < 2; j++) {
      const unsigned short* base =
          &Bs[d][hB][(rBb + jh * 32 + j * 16 + r16) * 64];
      bfr[j][0] = *(const short8*)(base + slot0 * 8);
      bfr[j][1] = *(const short8*)(base + slot1 * 8);
    }
  };
  auto mfma16 = [&](int i0, int j0, short8 (&bfr)[2][2]) {
    #pragma unroll
    for (int i = 0; i < 4; i++)
      #pragma unroll
      for (int j = 0; j < 2; j++) {
        acc[i0 + i][j0 + j] = __builtin_amdgcn_mfma_f32_16x16x32_bf16(
            af[i][0], bfr[j][0], acc[i0 + i][j0 + j], 0, 0, 0);
        acc[i0 + i][j0 + j] = __builtin_amdgcn_mfma_f32_16x16x32_bf16(
            af[i][1], bfr[j][1], acc[i0 + i][j0 + j], 0, 0, 0);
      }
  };

  // Prologue: tile0 complete into buf0 (8 loads), then B0,B1,A0 of tile1
  // (6 loads, stay in flight) -> matches steady state entering P1.
  stB(0, 0, 0); stB(0, 1, 0); stA(0, 0, 0); stA(0, 1, 0);
  stB(1, 0, 1); stB(1, 1, 1); stA(1, 0, 1);
  asm volatile("s_waitcnt vmcnt(6)" ::: "memory");  // tile0 landed
  __builtin_amdgcn_s_barrier();

  for (int it = 0; it < 32; ++it) {
    const int T = it * 2;
    // P1: (i-lo, j-lo) of buf0
    ldAh(0, 0); ldBh(0, 0, bl);
    stA(1, 1, T + 1);
    phase_mid(); mfma16(0, 0, bl); phase_end();
    // P2: (i-lo, j-hi)
    ldBh(0, 1, bh);
    phase_mid(); mfma16(0, 2, bh); phase_end();
    // P3: (i-hi, j-hi)
    ldAh(0, 1);
    stB(0, 0, T + 2);
    phase_mid(); mfma16(4, 2, bh); phase_end();
    // P4: (i-hi, j-lo)  [gate: buf1 = tile T+1 fully landed]
    stB(0, 1, T + 2);
    stA(0, 0, T + 2);
    asm volatile("s_waitcnt vmcnt(6)" ::: "memory");
    phase_mid(); mfma16(4, 0, bl); phase_end();
    // P5: (i-lo, j-lo) of buf1
    ldAh(1, 0); ldBh(1, 0, bl);
    stA(0, 1, T + 2);
    phase_mid(); mfma16(0, 0, bl); phase_end();
    // P6: (i-lo, j-hi)
    ldBh(1, 1, bh);
    phase_mid(); mfma16(0, 2, bh); phase_end();
    // P7: (i-hi, j-hi)
    ldAh(1, 1);
    stB(1, 0, T + 3);
    phase_mid(); mfma16(4, 2, bh); phase_end();
    // P8: (i-hi, j-lo)  [gate]
    stB(1, 1, T + 3);
    stA(1, 0, T + 3);
    asm volatile("s_waitcnt vmcnt(6)" ::: "memory");
    phase_mid(); mfma16(4, 0, bl); phase_end();
  }

  // drain pending LDS-DMA before epilogue / wave exit
  asm volatile("s_waitcnt vmcnt(0)" ::: "memory");

  // Epilogue. C/D layout: col = lane&15, row = quad*4 + reg.
  unsigned short* O = Out + (size_t)(m0 + hA * 128) * NTOT_ + n0 + (w & 3) * 64;
  #pragma unroll
  for (int i = 0; i < 8; i++)
    #pragma unroll
    for (int v = 0; v < 4; v++) {
      const int m = i * 16 + quad * 4 + v;
      #pragma unroll
      for (int j = 0; j < 4; j++)
        O[(size_t)m * NTOT_ + j * 16 + r16] = f2bf(acc[i][j][v]);
    }
}

// ---------------- BT-GEMM (128x128, 2-phase) — used for GEMM2 ----------------
template <bool BIAS>
__global__ __launch_bounds__(256, 2)
void gemm_bt(const unsigned short* __restrict__ A,
             const unsigned short* __restrict__ Bt,
             void* __restrict__ OutV,
             const float* __restrict__ bias,
             size_t bStride, size_t outStride) {
  __shared__ unsigned short As[128 * 64];
  __shared__ unsigned short Bs[128 * 64];
  const int b  = blockIdx.x;
  const int m0 = blockIdx.y * 128;
  const int c0 = blockIdx.z * 128;
  const int t = threadIdx.x;
  const int lane = t & 63;
  const int w = t >> 6;
  const int wm = (w & 1) * 64;
  const int wn = (w >> 1) * 64;
  const int quad = lane >> 4;
  const int r16  = lane & 15;

  const unsigned short* Bb = Bt + (size_t)b * bStride;

  f32x4 acc[4][4];
  #pragma unroll
  for (int i = 0; i < 4; i++)
    #pragma unroll
    for (int j = 0; j < 4; j++)
      acc[i][j] = (f32x4){0.f, 0.f, 0.f, 0.f};

  const int rs = t >> 3;
  const int q8 = (t & 7) ^ (rs & 7);
  const unsigned short* aSrc = A  + (size_t)(m0 + rs) * 4096 + q8 * 8;
  const unsigned short* bSrc = Bb + (size_t)(c0 + rs) * 4096 + q8 * 8;
  unsigned short* aDst = As + t * 8;
  unsigned short* bDst = Bs + t * 8;

  for (int k0 = 0; k0 < 4096; k0 += 64) {
    #pragma unroll
    for (int p = 0; p < 4; p++) {
      gl2lds16(aSrc + (size_t)p * 32 * 4096 + k0, aDst + p * 2048);
      gl2lds16(bSrc + (size_t)p * 32 * 4096 + k0, bDst + p * 2048);
    }
    __syncthreads();
    #pragma unroll
    for (int kk = 0; kk < 2; kk++) {
      short8 af[4], bfv[4];
      const int cb = kk * 4 + quad;
      #pragma unroll
      for (int i = 0; i < 4; i++) {
        int ra = wm + i * 16 + r16;
        af[i]  = *(const short8*)(As + ra * 64 + ((cb ^ (ra & 7)) * 8));
        int rb = wn + i * 16 + r16;
        bfv[i] = *(const short8*)(Bs + rb * 64 + ((cb ^ (rb & 7)) * 8));
      }
      #pragma unroll
      for (int i = 0; i < 4; i++)
        #pragma unroll
        for (int j = 0; j < 4; j++)
          acc[i][j] = __builtin_amdgcn_mfma_f32_16x16x32_bf16(
              af[i], bfv[j], acc[i][j], 0, 0, 0);
    }
    __syncthreads();
  }

  if (BIAS) {
    float* Out = (float*)OutV + (size_t)b * outStride;
    #pragma unroll
    for (int i = 0; i < 4; i++) {
      #pragma unroll
      for (int v = 0; v < 4; v++) {
        int m = m0 + wm + i * 16 + quad * 4 + v;
        float bi = bias[m];
        #pragma unroll
        for (int j = 0; j < 4; j++) {
          int c = c0 + wn + j * 16 + r16;
          Out[(size_t)m * C_ + c] = acc[i][j][v] + bi;
        }
      }
    }
  } else {
    unsigned short* Out = (unsigned short*)OutV + (size_t)b * outStride;
    #pragma unroll
    for (int i = 0; i < 4; i++) {
      #pragma unroll
      for (int v = 0; v < 4; v++) {
        int m = m0 + wm + i * 16 + quad * 4 + v;
        #pragma unroll
        for (int j = 0; j < 4; j++) {
          int c = c0 + wn + j * 16 + r16;
          Out[(size_t)m * C_ + c] = f2bf(acc[i][j][v]);
        }
      }
    }
  }
}

// ---------------- middle: norms + kernel-trick + gelu -> GT ------------------
// Y [12288, 6144] bf16: rows 0..4095 q, 4096..8191 k, 8192..12287 v
//   (row m = h*512 + n' within each third); column j = b*384 + c
// GT[b] bf16 [384, 4096]: GT[c][h*512+n'] = gelu(qhat * kt)
__global__ __launch_bounds__(512)
void middle(const unsigned short* __restrict__ Y,
            unsigned short* __restrict__ GT,
            const float* __restrict__ scale) {
  const int h = blockIdx.x;
  const int b = blockIdx.y;
  const unsigned short* Q = Y + (size_t)(h * NH_) * NTOT_ + b * C_;
  const unsigned short* K = Y + (size_t)(N_ + h * NH_) * NTOT_ + b * C_;
  const unsigned short* V = Y + (size_t)(2 * N_ + h * NH_) * NTOT_ + b * C_;
  unsigned short* GTb = GT + (size_t)b * C_ * N_ + h * NH_;

  __shared__ float invq[C_], invk[C_], kt[NH_];
  const int t = threadIdx.x;
  const float sc = scale[h];

  // Phase A: per-column (c) sum of squares over 512 rows
  if (t < C_) {
    float sq = 0.f, sk = 0.f;
    for (int n = 0; n < NH_; n++) {
      float qv = bf2f(Q[(size_t)n * NTOT_ + t]);
      float kv = bf2f(K[(size_t)n * NTOT_ + t]);
      sq += qv * qv;
      sk += kv * kv;
    }
    invq[t] = rsqrtf(sq);
    invk[t] = rsqrtf(sk);
  }
  __syncthreads();

  // Phase B: kt[n'] = scale * sum_c khat[n'][c] * v[n'][c]
  {
    int w = t >> 6, l = t & 63;
    for (int n = w; n < NH_; n += 8) {
      float s = 0.f;
      for (int c = l; c < C_; c += 64)
        s += bf2f(K[(size_t)n * NTOT_ + c]) * invk[c] *
             bf2f(V[(size_t)n * NTOT_ + c]);
      #pragma unroll
      for (int o = 32; o > 0; o >>= 1) s += __shfl_xor(s, o);
      if (l == 0) kt[n] = s * sc;
    }
  }
  __syncthreads();

  // Phase C: GT[c][h*512+n] = gelu(qhat[n][c] * kt[n])
  {
    int n = t;
    float ktv = kt[n];
    for (int c = 0; c < C_; c++) {
      float xv = bf2f(Q[(size_t)n * NTOT_ + c]) * invq[c] * ktv;
      float g = 0.5f * xv * (1.0f + erff(xv * 0.70710678118654752f));
      GTb[(size_t)c * N_ + n] = f2bf(g);
    }
  }
}

extern "C" void kernel_launch(void* const* d_in, const int* in_sizes, int n_in,
                              void* d_out, int out_size, void* d_ws, size_t ws_size,
                              hipStream_t stream) {
  const float* x     = (const float*)d_in[0];
  const float* wq    = (const float*)d_in[1];
  const float* wkv   = (const float*)d_in[2];
  const float* wproj = (const float*)d_in[3];
  const float* bproj = (const float*)d_in[4];
  const float* scale = (const float*)d_in[5];

  // Workspace layout (bf16 buffers), total ~386 MB — identical sizes to prior
  unsigned short* Wqkv = (unsigned short*)d_ws;                 // [12288,4096]
  unsigned short* Wp   = Wqkv + (size_t)12288 * 4096;           // [4096,4096]
  unsigned short* xT   = Wp   + (size_t)4096 * 4096;            // [16,384,4096] = [6144,4096]
  unsigned short* Y    = xT   + (size_t)B_ * C_ * N_;           // [12288,6144]
  unsigned short* GT   = Y    + (size_t)12288 * NTOT_;          // [16,384,4096]

  const size_t nq  = (size_t)4096 * 4096;
  const size_t nkv = (size_t)8192 * 4096;

  cvt_f32_bf16<<<(int)(nq  / 8 / 256), 256, 0, stream>>>(wq,    Wqkv,      nq);
  cvt_f32_bf16<<<(int)(nkv / 8 / 256), 256, 0, stream>>>(wkv,   Wqkv + nq, nkv);
  cvt_f32_bf16<<<(int)(nq  / 8 / 256), 256, 0, stream>>>(wproj, Wp,        nq);

  transpose_x<<<dim3(64, 6, 16), 256, 0, stream>>>(x, xT);

  // GEMM1 (merged batch): Y = Wqkv @ xT_all^T   [12288,6144] bf16
  gemm256_bt<<<dim3(48 * 24), 512, 0, stream>>>(Wqkv, xT, Y);

  middle<<<dim3(8, 16), 512, 0, stream>>>(Y, GT, scale);

  // GEMM2: out[b] = Wproj @ GT[b]^T + bproj  (fp32 out, final layout [B,N,C])
  gemm_bt<true><<<dim3(16, 32, 3), 256, 0, stream>>>(
      Wp, GT, d_out, bproj, (size_t)C_ * N_, (size_t)N_ * C_);
}

// Round 3
// 1206.225 us; speedup vs baseline: 1.2041x; 1.2041x over previous
//
#include <hip/hip_runtime.h>
#include <math.h>
#include <stdint.h>

// Problem constants
#define B_ 16
#define N_ 4096
#define C_ 384
#define H_ 8
#define NH_ 512

typedef __attribute__((ext_vector_type(8))) short short8;
typedef __attribute__((ext_vector_type(4))) float f32x4;

__device__ __forceinline__ unsigned short f2bf(float x) {
  uint32_t u = __builtin_bit_cast(uint32_t, x);
  uint32_t r = (u + 0x7fffu + ((u >> 16) & 1u)) >> 16;
  return (unsigned short)r;
}
__device__ __forceinline__ float bf2f(unsigned short u) {
  uint32_t v = ((uint32_t)u) << 16;
  return __builtin_bit_cast(float, v);
}

__device__ __forceinline__ void gl2lds16(const void* g, void* l) {
  __builtin_amdgcn_global_load_lds((__attribute__((address_space(1))) void*)g,
                                   (__attribute__((address_space(3))) void*)l,
                                   16, 0, 0);
}

// ---------------- fp32 -> bf16 cast (vectorized, 8 elems/thread) -------------
__global__ void cvt_f32_bf16(const float* __restrict__ src,
                             unsigned short* __restrict__ dst, size_t n) {
  size_t i = ((size_t)blockIdx.x * blockDim.x + threadIdx.x) * 8;
  if (i >= n) return;
  float4 a = *(const float4*)(src + i);
  float4 b = *(const float4*)(src + i + 4);
  typedef __attribute__((ext_vector_type(8))) unsigned short u16x8;
  u16x8 o;
  o[0] = f2bf(a.x); o[1] = f2bf(a.y); o[2] = f2bf(a.z); o[3] = f2bf(a.w);
  o[4] = f2bf(b.x); o[5] = f2bf(b.y); o[6] = f2bf(b.z); o[7] = f2bf(b.w);
  *(u16x8*)(dst + i) = o;
}

// ---------------- x [B,4096,384] f32 -> xT [B,384,4096] bf16 -----------------
__global__ __launch_bounds__(256)
void transpose_x(const float* __restrict__ x, unsigned short* __restrict__ xT) {
  __shared__ float tile[64 * 65];
  int b = blockIdx.z;
  int n0 = blockIdx.x * 64;
  int c0 = blockIdx.y * 64;
  int t = threadIdx.x;
  const float* xb = x + (size_t)b * N_ * C_;
  #pragma unroll
  for (int i = 0; i < 16; i++) {
    int r = i * 4 + (t >> 6);   // row within n-tile
    int cc = t & 63;            // col within c-tile
    tile[r * 65 + cc] = xb[(size_t)(n0 + r) * C_ + c0 + cc];
  }
  __syncthreads();
  unsigned short* xTb = xT + (size_t)b * C_ * N_;
  #pragma unroll
  for (int i = 0; i < 16; i++) {
    int r = i * 4 + (t >> 6);   // row within c-tile (output row)
    int nn = t & 63;            // col within n-tile
    xTb[(size_t)(c0 + r) * N_ + n0 + nn] = f2bf(tile[nn * 65 + r]);
  }
}

// ---------------- BT-GEMM: Out[b] = A @ Bt[b]^T (+bias) ----------------------
// A   [MA, 4096] bf16 row-major (K-contiguous)
// Bt  [.., 384, 4096] bf16 per-batch (K-contiguous)  -> logical B[k][c]
// Out bf16 [MA,384] (no bias) or f32 [MA,384] (+bias[m])
// Tile 128x128, BK=64, 4 waves each 64x64 via 4x4 of 16x16x32 MFMA.
// LDS XOR-swizzle: chunk slot(r, c8) = r*8 + (c8 ^ (r&7)); staging stays
// lane-contiguous (global_load_lds requirement), frag ds_read_b128 <=2-way.
template <bool BIAS>
__global__ __launch_bounds__(256, 2)
void gemm_bt(const unsigned short* __restrict__ A,
             const unsigned short* __restrict__ Bt,
             void* __restrict__ OutV,
             const float* __restrict__ bias,
             size_t bStride, size_t outStride) {
  __shared__ unsigned short As[128 * 64];
  __shared__ unsigned short Bs[128 * 64];
  const int b  = blockIdx.x;          // batch fastest: 16 blocks share A-tile
  const int m0 = blockIdx.y * 128;
  const int c0 = blockIdx.z * 128;
  const int t = threadIdx.x;
  const int lane = t & 63;
  const int w = t >> 6;
  const int wm = (w & 1) * 64;
  const int wn = (w >> 1) * 64;
  const int quad = lane >> 4;
  const int r16  = lane & 15;

  const unsigned short* Bb = Bt + (size_t)b * bStride;

  f32x4 acc[4][4];
  #pragma unroll
  for (int i = 0; i < 4; i++)
    #pragma unroll
    for (int j = 0; j < 4; j++)
      acc[i][j] = (f32x4){0.f, 0.f, 0.f, 0.f};

  const int rs = t >> 3;                    // staging row 0..31
  const int q8 = (t & 7) ^ (rs & 7);        // swizzled logical k-chunk
  const unsigned short* aSrc = A  + (size_t)(m0 + rs) * 4096 + q8 * 8;
  const unsigned short* bSrc = Bb + (size_t)(c0 + rs) * 4096 + q8 * 8;
  unsigned short* aDst = As + t * 8;
  unsigned short* bDst = Bs + t * 8;

  for (int k0 = 0; k0 < 4096; k0 += 64) {
    #pragma unroll
    for (int p = 0; p < 4; p++) {
      gl2lds16(aSrc + (size_t)p * 32 * 4096 + k0, aDst + p * 2048);
      gl2lds16(bSrc + (size_t)p * 32 * 4096 + k0, bDst + p * 2048);
    }
    __syncthreads();
    #pragma unroll
    for (int kk = 0; kk < 2; kk++) {
      short8 af[4], bfv[4];
      const int cb = kk * 4 + quad;         // logical chunk index 0..7
      #pragma unroll
      for (int i = 0; i < 4; i++) {
        int ra = wm + i * 16 + r16;
        af[i]  = *(const short8*)(As + ra * 64 + ((cb ^ (ra & 7)) * 8));
        int rb = wn + i * 16 + r16;
        bfv[i] = *(const short8*)(Bs + rb * 64 + ((cb ^ (rb & 7)) * 8));
      }
      #pragma unroll
      for (int i = 0; i < 4; i++)
        #pragma unroll
        for (int j = 0; j < 4; j++)
          acc[i][j] = __builtin_amdgcn_mfma_f32_16x16x32_bf16(
              af[i], bfv[j], acc[i][j], 0, 0, 0);
    }
    __syncthreads();
  }

  // Epilogue. C/D layout: col = lane&15, row = quad*4 + reg.
  if (BIAS) {
    float* Out = (float*)OutV + (size_t)b * outStride;
    #pragma unroll
    for (int i = 0; i < 4; i++) {
      #pragma unroll
      for (int v = 0; v < 4; v++) {
        int m = m0 + wm + i * 16 + quad * 4 + v;
        float bi = bias[m];
        #pragma unroll
        for (int j = 0; j < 4; j++) {
          int c = c0 + wn + j * 16 + r16;
          Out[(size_t)m * C_ + c] = acc[i][j][v] + bi;
        }
      }
    }
  } else {
    unsigned short* Out = (unsigned short*)OutV + (size_t)b * outStride;
    #pragma unroll
    for (int i = 0; i < 4; i++) {
      #pragma unroll
      for (int v = 0; v < 4; v++) {
        int m = m0 + wm + i * 16 + quad * 4 + v;
        #pragma unroll
        for (int j = 0; j < 4; j++) {
          int c = c0 + wn + j * 16 + r16;
          Out[(size_t)m * C_ + c] = f2bf(acc[i][j][v]);
        }
      }
    }
  }
}

// ---------------- middle, split for full-GPU parallelism ---------------------
// Y[b] bf16 [12288, 384]: rows 0..4095 q, 4096..8191 k, 8192..12287 v
//   (row m = h*512 + n' within each third)
//
// mid_stats: grid (B=16, H=8, 2) = 256 blocks, 384 threads.
//   z=0: invG[0][b][h][c] = rsqrt(sum_n Q[n][c]^2)
//   z=1: invG[1][b][h][c] = rsqrt(sum_n K[n][c]^2)
// Coalesced: wave reads 64 consecutive columns of one row per iteration.
__global__ __launch_bounds__(384)
void mid_stats(const unsigned short* __restrict__ Y,
               float* __restrict__ invG) {
  const int b = blockIdx.x, h = blockIdx.y, z = blockIdx.z;
  const unsigned short* M =
      Y + (size_t)b * 12288 * C_ + (size_t)(z * N_ + h * NH_) * C_;
  const int c = threadIdx.x;
  float s = 0.f;
  for (int n = 0; n < NH_; n++) {
    float v = bf2f(M[(size_t)n * C_ + c]);
    s += v * v;
  }
  invG[((size_t)z * 128 + b * 8 + h) * C_ + c] = rsqrtf(s);
}

// mid_apply: grid (B=16, H=8, 2) = 256 blocks, 512 threads; z = n-half (256 n).
//   kt[n] = scale * sum_c (K[n][c]*invK[c]) * V[n][c]    (wave-per-row)
//   GT[b][c][h*512+n] = gelu(Q[n][c] * invQ[c] * kt[n])  (2-way c-split per n)
__global__ __launch_bounds__(512)
void mid_apply(const unsigned short* __restrict__ Y,
               unsigned short* __restrict__ GT,
               const float* __restrict__ invG,
               const float* __restrict__ scale) {
  const int b = blockIdx.x, h = blockIdx.y, z = blockIdx.z;
  const unsigned short* Yb = Y + (size_t)b * 12288 * C_;
  const unsigned short* Q = Yb + (size_t)(h * NH_) * C_;
  const unsigned short* K = Yb + (size_t)(N_ + h * NH_) * C_;
  const unsigned short* V = Yb + (size_t)(2 * N_ + h * NH_) * C_;
  const float* invQ = invG + ((size_t)b * 8 + h) * C_;
  const float* invK = invG + ((size_t)128 + b * 8 + h) * C_;
  unsigned short* GTb = GT + (size_t)b * C_ * N_ + h * NH_;

  __shared__ float kts[256];
  const int t = threadIdx.x;
  const float sc = scale[h];
  const int n0 = z * 256;

  // kt for this block's 256 rows: 8 waves x 32 rows each, lane-over-c reduce
  {
    const int w = t >> 6, l = t & 63;
    for (int i = 0; i < 32; i++) {
      const int n = n0 + w * 32 + i;
      float s = 0.f;
      #pragma unroll
      for (int ci = 0; ci < 6; ci++) {
        const int c = l + ci * 64;
        s += bf2f(K[(size_t)n * C_ + c]) * invK[c] * bf2f(V[(size_t)n * C_ + c]);
      }
      #pragma unroll
      for (int o = 32; o > 0; o >>= 1) s += __shfl_xor(s, o);
      if (l == 0) kts[n - n0] = s * sc;
    }
  }
  __syncthreads();

  // gelu + transposed write: thread t -> n = n0+(t&255), c-range half (t>>8)
  {
    const int n = n0 + (t & 255);
    const int c0 = (t >> 8) * 192;
    const float ktv = kts[n - n0];
    for (int c = c0; c < c0 + 192; c++) {
      float xv = bf2f(Q[(size_t)n * C_ + c]) * invQ[c] * ktv;
      float g = 0.5f * xv * (1.0f + erff(xv * 0.70710678118654752f));
      GTb[(size_t)c * N_ + n] = f2bf(g);
    }
  }
}

extern "C" void kernel_launch(void* const* d_in, const int* in_sizes, int n_in,
                              void* d_out, int out_size, void* d_ws, size_t ws_size,
                              hipStream_t stream) {
  const float* x     = (const float*)d_in[0];
  const float* wq    = (const float*)d_in[1];
  const float* wkv   = (const float*)d_in[2];
  const float* wproj = (const float*)d_in[3];
  const float* bproj = (const float*)d_in[4];
  const float* scale = (const float*)d_in[5];

  // Workspace layout (bf16 buffers), total ~386 MB
  unsigned short* Wqkv = (unsigned short*)d_ws;                 // [12288,4096]
  unsigned short* Wp   = Wqkv + (size_t)12288 * 4096;           // [4096,4096]
  unsigned short* xT   = Wp   + (size_t)4096 * 4096;            // [16,384,4096]
  unsigned short* Y    = xT   + (size_t)B_ * C_ * N_;           // [16,12288,384]
  unsigned short* GT   = Y    + (size_t)B_ * 12288 * C_;        // [16,384,4096]
  // invG [2][16][8][384] f32 overlaps Wqkv: written only after GEMM1 has
  // finished reading Wqkv (stream-ordered), never read by later GEMMs.
  float* invG = (float*)Wqkv;

  const size_t nq  = (size_t)4096 * 4096;
  const size_t nkv = (size_t)8192 * 4096;

  cvt_f32_bf16<<<(int)(nq  / 8 / 256), 256, 0, stream>>>(wq,    Wqkv,      nq);
  cvt_f32_bf16<<<(int)(nkv / 8 / 256), 256, 0, stream>>>(wkv,   Wqkv + nq, nkv);
  cvt_f32_bf16<<<(int)(nq  / 8 / 256), 256, 0, stream>>>(wproj, Wp,        nq);

  transpose_x<<<dim3(64, 6, 16), 256, 0, stream>>>(x, xT);

  // GEMM1: Y[b] = Wqkv @ xT[b]^T   (bf16 out)
  gemm_bt<false><<<dim3(16, 96, 3), 256, 0, stream>>>(
      Wqkv, xT, Y, nullptr, (size_t)C_ * N_, (size_t)12288 * C_);

  mid_stats<<<dim3(16, 8, 2), 384, 0, stream>>>(Y, invG);
  mid_apply<<<dim3(16, 8, 2), 512, 0, stream>>>(Y, GT, invG, scale);

  // GEMM2: out[b] = Wproj @ GT[b]^T + bproj  (fp32 out, final layout [B,N,C])
  gemm_bt<true><<<dim3(16, 32, 3), 256, 0, stream>>>(
      Wp, GT, d_out, bproj, (size_t)C_ * N_, (size_t)N_ * C_);
}